// Round 1
// baseline (41511.765 us; speedup 1.0000x reference)
//
#include <hip/hip_runtime.h>
#include <hip/hip_bf16.h>
#include <math.h>

#define BB 64
#define TT 1024
#define EE 256
#define HH 512

// ws layout (floats)
#define H0_OFF   0          // [2][64][512]
#define H1_OFF   65536      // [2][64][512]
#define RH0_OFF  131072     // [64][512]
#define RH1_OFF  163840     // [64][512]
#define CTR_FLT  196608     // counters live after this (as ints)
#define WS_BYTES (786432 + 8*256)

__device__ __forceinline__ float gload(const float* p) {
    return __hip_atomic_load(p, __ATOMIC_RELAXED, __HIP_MEMORY_SCOPE_AGENT);
}
__device__ __forceinline__ void gstore(float* p, float v) {
    __hip_atomic_store(p, v, __ATOMIC_RELAXED, __HIP_MEMORY_SCOPE_AGENT);
}
__device__ __forceinline__ float hsum(float4 v) { return (v.x + v.y) + (v.z + v.w); }
__device__ __forceinline__ float sigm(float x) { return 1.f / (1.f + expf(-x)); }

__device__ __forceinline__ void dot2(const float* __restrict__ w1,
                                     const float* __restrict__ w2,
                                     const float* __restrict__ x, int n,
                                     float4& a1, float4& a2) {
    #pragma unroll 4
    for (int k = 0; k < n; k += 4) {
        float4 xv = *(const float4*)(x + k);
        float4 wa = *(const float4*)(w1 + k);
        float4 wb = *(const float4*)(w2 + k);
        a1.x = fmaf(wa.x, xv.x, a1.x); a1.y = fmaf(wa.y, xv.y, a1.y);
        a1.z = fmaf(wa.z, xv.z, a1.z); a1.w = fmaf(wa.w, xv.w, a1.w);
        a2.x = fmaf(wb.x, xv.x, a2.x); a2.y = fmaf(wb.y, xv.y, a2.y);
        a2.z = fmaf(wb.z, xv.z, a2.z); a2.w = fmaf(wb.w, xv.w, a2.w);
    }
}
__device__ __forceinline__ void dot1(const float* __restrict__ w1,
                                     const float* __restrict__ x, int n, float4& a1) {
    #pragma unroll 4
    for (int k = 0; k < n; k += 4) {
        float4 xv = *(const float4*)(x + k);
        float4 wa = *(const float4*)(w1 + k);
        a1.x = fmaf(wa.x, xv.x, a1.x); a1.y = fmaf(wa.y, xv.y, a1.y);
        a1.z = fmaf(wa.z, xv.z, a1.z); a1.w = fmaf(wa.w, xv.w, a1.w);
    }
}

__device__ __forceinline__ void domain_barrier(int* ctr, int target) {
    __syncthreads();
    if (threadIdx.x == 0) {
        // RELEASE: drains our sc1 data stores before the arrival is visible.
        __hip_atomic_fetch_add(ctr, 1, __ATOMIC_RELEASE, __HIP_MEMORY_SCOPE_AGENT);
        // Relaxed spin: no acquire-invalidate, keeps clean weight lines in L2.
        while (__hip_atomic_load(ctr, __ATOMIC_RELAXED, __HIP_MEMORY_SCOPE_AGENT) < target)
            __builtin_amdgcn_s_sleep(1);
    }
    __syncthreads();
}

__global__ __launch_bounds__(256) void gru_main(
    const int* __restrict__ tokens, const float* __restrict__ emb,
    const float* __restrict__ Wr0, const float* __restrict__ br0,
    const float* __restrict__ Wz0, const float* __restrict__ bz0,
    const float* __restrict__ Wh0, const float* __restrict__ bh0,
    const float* __restrict__ Wr1, const float* __restrict__ br1,
    const float* __restrict__ Wz1, const float* __restrict__ bz1,
    const float* __restrict__ Wh1, const float* __restrict__ bh1,
    float* __restrict__ ws)
{
    const int blk = blockIdx.x;
    const int g = blk >> 5;       // batch group 0..7
    const int j = blk & 31;       // column slice 0..31 (j%8 = XCD -> L2 slice affinity)
    const int tid = threadIdx.x;
    const bool isL1 = tid >= 128;
    const int lt = tid & 127;
    const int lb = lt & 7;        // local batch row 0..7
    const int ci = lt >> 3;       // 0..15
    const int c = j * 16 + ci;    // hidden column owned by this thread
    const int bg = g * 8 + lb;    // global batch row

    float* h0buf = ws + H0_OFF;
    float* h1buf = ws + H1_OFF;
    float* rh0 = ws + RH0_OFF;
    float* rh1 = ws + RH1_OFF;
    int* ctr = (int*)(ws + CTR_FLT) + g * 64;

    const float* Wr = isL1 ? Wr1 : Wr0;
    const float* Wz = isL1 ? Wz1 : Wz0;
    const float* Wh = isL1 ? Wh1 : Wh0;
    const int K = isL1 ? 1024 : 768;
    const int len1 = isL1 ? 512 : 256;
    const float* wrRow = Wr + (size_t)c * K;
    const float* wzRow = Wz + (size_t)c * K;
    const float* whRow = Wh + (size_t)c * K;
    const float bR = (isL1 ? br1 : br0)[c];
    const float bZ = (isL1 ? bz1 : bz0)[c];
    const float bH = (isL1 ? bh1 : bh0)[c];

    // Rows padded so lanes with different b hit different bank quads (b128 reads)
    __shared__ float sx[8][260];    // x_t   (L0 K-seg 1)
    __shared__ float sh0[8][516];   // h0 prev / h0_t (shared by L0 seg2 and L1 seg1)
    __shared__ float sh1[8][516];   // h1 prev, later overwritten with rh1
    __shared__ float srh[8][516];   // rh0

    // staging map: each thread stages 16 (or 8) contiguous elements of one row
    const int sb = tid >> 5;              // row 0..7
    const int sk16 = (tid & 31) * 16;
    const int sk8 = (tid & 31) * 8;
    const int sbg = g * 8 + sb;

    int target = 32;
    for (int s = 0; s <= 1024; ++s) {
        const int rd0 = (s & 1) ^ 1;   // h0 read slot
        // ---- P1 staging ----
        {
            const float* src0 = h0buf + rd0 * 32768 + sbg * 512 + sk16;
            const float* src1 = h1buf + (s & 1) * 32768 + sbg * 512 + sk16;
            #pragma unroll
            for (int i = 0; i < 16; i++) sh0[sb][sk16 + i] = gload(src0 + i);
            #pragma unroll
            for (int i = 0; i < 16; i++) sh1[sb][sk16 + i] = gload(src1 + i);
            if (s < 1024) {
                int tok = tokens[sbg * 1024 + s];
                const float4* er = (const float4*)(emb + (size_t)tok * 256 + sk8);
                float4 e0 = er[0], e1 = er[1];
                *(float4*)&sx[sb][sk8] = e0;
                *(float4*)&sx[sb][sk8 + 4] = e1;
            }
        }
        __syncthreads();

        const bool act = isL1 ? (s >= 1) : (s < 1024);
        const float* s1 = isL1 ? &sh0[lb][0] : &sx[lb][0];
        const float* s2 = isL1 ? &sh1[lb][0] : &sh0[lb][0];

        float zv = 0.f, hp = 0.f;
        if (act) {
            float4 aR = {0, 0, 0, 0}, aZ = {0, 0, 0, 0};
            dot2(wrRow, wzRow, s1, len1, aR, aZ);
            dot2(wrRow + len1, wzRow + len1, s2, 512, aR, aZ);
            float rv = sigm(hsum(aR) + bR);
            zv = sigm(hsum(aZ) + bZ);
            hp = s2[c];                     // h_prev for this thread's column
            float* rhb = isL1 ? rh1 : rh0;
            gstore(rhb + bg * 512 + c, rv * hp);
        }
        domain_barrier(ctr, target); target += 32;

        // ---- P2 staging (rh0 -> srh, rh1 -> sh1) ----
        {
            const float* src0 = rh0 + sbg * 512 + sk16;
            const float* src1 = rh1 + sbg * 512 + sk16;
            #pragma unroll
            for (int i = 0; i < 16; i++) srh[sb][sk16 + i] = gload(src0 + i);
            #pragma unroll
            for (int i = 0; i < 16; i++) sh1[sb][sk16 + i] = gload(src1 + i);
        }
        __syncthreads();

        if (act) {
            const float* s2p = isL1 ? &sh1[lb][0] : &srh[lb][0];
            float4 aH = {0, 0, 0, 0};
            dot1(whRow, s1, len1, aH);
            dot1(whRow + len1, s2p, 512, aH);
            float ht = tanhf(hsum(aH) + bH);
            float hn = (1.f - zv) * hp + zv * ht;
            float* hb = isL1 ? (h1buf + ((s - 1) & 1) * 32768)
                             : (h0buf + (s & 1) * 32768);
            gstore(hb + bg * 512 + c, hn);
        }
        domain_barrier(ctr, target); target += 32;
    }
}

__global__ __launch_bounds__(128) void gru_fc(
    const float* __restrict__ h1f, const float* __restrict__ fcW,
    const float* __restrict__ fcb, float* __restrict__ out)
{
    int tid = threadIdx.x;
    if (tid >= 128) return;
    int b = tid >> 1, c = tid & 1;
    const float* hrow = h1f + b * 512;
    const float* wrow = fcW + c * 512;
    float4 a = {0, 0, 0, 0};
    #pragma unroll 4
    for (int k = 0; k < 512; k += 4) {
        float4 hv = *(const float4*)(hrow + k);
        float4 wv = *(const float4*)(wrow + k);
        a.x = fmaf(hv.x, wv.x, a.x); a.y = fmaf(hv.y, wv.y, a.y);
        a.z = fmaf(hv.z, wv.z, a.z); a.w = fmaf(hv.w, wv.w, a.w);
    }
    out[b * 2 + c] = hsum(a) + fcb[c];
}

extern "C" void kernel_launch(void* const* d_in, const int* in_sizes, int n_in,
                              void* d_out, int out_size, void* d_ws, size_t ws_size,
                              hipStream_t stream) {
    const int* tokens = (const int*)d_in[0];
    const float* emb = (const float*)d_in[1];
    const float* Wr0 = (const float*)d_in[2];  const float* br0 = (const float*)d_in[3];
    const float* Wz0 = (const float*)d_in[4];  const float* bz0 = (const float*)d_in[5];
    const float* Wh0 = (const float*)d_in[6];  const float* bh0 = (const float*)d_in[7];
    const float* Wr1 = (const float*)d_in[8];  const float* br1 = (const float*)d_in[9];
    const float* Wz1 = (const float*)d_in[10]; const float* bz1 = (const float*)d_in[11];
    const float* Wh1 = (const float*)d_in[12]; const float* bh1 = (const float*)d_in[13];
    const float* fcW = (const float*)d_in[14]; const float* fcb = (const float*)d_in[15];
    float* ws = (float*)d_ws;

    // zero h/rh buffers and barrier counters (ws is poisoned 0xAA before every call)
    hipMemsetAsync(d_ws, 0, WS_BYTES, stream);

    gru_main<<<256, 256, 0, stream>>>(tokens, emb, Wr0, br0, Wz0, bz0, Wh0, bh0,
                                      Wr1, br1, Wz1, bz1, Wh1, bh1, ws);
    // final hidden state of layer 1: t=1023 -> slot 1
    gru_fc<<<1, 128, 0, stream>>>(ws + H1_OFF + 32768, fcW, fcb, (float*)d_out);
}